// Round 6
// baseline (69.964 us; speedup 1.0000x reference)
//
#include <hip/hip_runtime.h>
#include <math.h>

#define MARGIN 0.3f
#define NJ 32   // column chunks (grid.y)

typedef short bf16x8 __attribute__((ext_vector_type(8)));
typedef float f32x4 __attribute__((ext_vector_type(4)));

__device__ __forceinline__ unsigned short f2bf_rne(float x) {
    unsigned b = __float_as_uint(x);
    unsigned r = b + 0x7FFFu + ((b >> 16) & 1u);
    return (unsigned short)(r >> 16);
}
__device__ __forceinline__ float bf2f(unsigned short h) {
    return __uint_as_float(((unsigned)h) << 16);
}
// family table {0,1,2,1,3,3} packed 2 bits/entry
__device__ __forceinline__ int fam_of(int lbl) { return (0xF64 >> (2 * lbl)) & 3; }

// ---------------- K1: deterministic counting sort by family ----------------
__global__ __launch_bounds__(1024) void sort_kernel(const int* __restrict__ labels,
                                                    int* __restrict__ posOf,
                                                    unsigned char* __restrict__ famSorted,
                                                    int* __restrict__ famLoHi, int B) {
    const int t = threadIdx.x;
    const int lane = t & 63, w = t >> 6;
    int lc[4] = {0, 0, 0, 0};
    int lf[8], lr[8];
#pragma unroll
    for (int j = 0; j < 8; j++) {
        int f = fam_of(labels[t * 8 + j]);
        lf[j] = f; lr[j] = lc[f]++;
    }
    int inc[4];
#pragma unroll
    for (int f = 0; f < 4; f++) {
        int v = lc[f];
#pragma unroll
        for (int o = 1; o < 64; o <<= 1) {
            int u = __shfl_up(v, o, 64);
            if (lane >= o) v += u;
        }
        inc[f] = v;
    }
    __shared__ int waveTot[16][4], waveBase[16][4], famBase[4], famTotS[4];
    if (lane == 63)
#pragma unroll
        for (int f = 0; f < 4; f++) waveTot[w][f] = inc[f];
    __syncthreads();
    if (t < 64) {
        int f = t >> 4, ww = t & 15;
        int v = waveTot[ww][f];
#pragma unroll
        for (int o = 1; o < 16; o <<= 1) {
            int u = __shfl_up(v, o, 64);
            if ((t & 15) >= o) v += u;
        }
        waveBase[ww][f] = v - waveTot[ww][f];
        if (ww == 15) famTotS[f] = v;
    }
    __syncthreads();
    if (t == 0) {
        int b = 0;
#pragma unroll
        for (int f = 0; f < 4; f++) {
            famBase[f] = b; famLoHi[f] = b; b += famTotS[f]; famLoHi[4 + f] = b;
        }
    }
    __syncthreads();
    int base[4];
#pragma unroll
    for (int f = 0; f < 4; f++) base[f] = famBase[f] + waveBase[w][f] + (inc[f] - lc[f]);
#pragma unroll
    for (int j = 0; j < 8; j++) {
        int pos = base[lf[j]] + lr[j];
        posOf[t * 8 + j] = pos;
        famSorted[pos] = (unsigned char)lf[j];
    }
}

// ---------------- K2: normalize + bf16 hi/lo split + merged packed scatter ----------------
// Merged strip layout (2048 bf16 = 4KB per 16-col strip):
//   [0,512):   hi, k 0..31   (frag h0 = elems lane*8..+8)
//   [512,1024): hi, k 32..63 (h1)
//   [1024,1536): lo, k 0..31 (l0)
//   [1536,2048): lo, k 32..63 (l1)
// within each 512: idx = ((k&31)>>3)*128 + col*8 + (k&7)
__global__ __launch_bounds__(256) void normpack_kernel(const float* __restrict__ emb,
                                                       const int* __restrict__ posOf,
                                                       short* __restrict__ pack, int B) {
    const int lane = threadIdx.x & 63;
    const int wid  = threadIdx.x >> 6;
    const int row  = blockIdx.x * 4 + wid;
    float x = emb[(size_t)row * 64 + lane];
    float ss = x * x;
#pragma unroll
    for (int o = 32; o > 0; o >>= 1) ss += __shfl_xor(ss, o, 64);
    float n = fmaxf(sqrtf(ss), 1e-12f);
    float v = x / n;
    unsigned short h = f2bf_rne(v);
    float lo = v - bf2f(h);
    unsigned short l = f2bf_rne(lo);
    int pos = posOf[row];
    size_t sidx = (size_t)(pos >> 4) * 2048 + (size_t)(lane >> 5) * 512 +
                  (size_t)((lane & 31) >> 3) * 128 + (size_t)(pos & 15) * 8 + (lane & 7);
    pack[sidx] = (short)h;
    pack[sidx + 1024] = (short)l;
}

// ---------------- K3: MFMA GEMM + masked min/max (pinned pipeline) ----------------
#define LOADB(H0, H1, L0, L1, JT)                                                    \
    do {                                                                             \
        const short* pB_ = pack + (size_t)(jStrip0 + (JT)) * 2048;                   \
        H0 = *(const bf16x8*)(pB_ + lane * 8);                                       \
        H1 = *(const bf16x8*)(pB_ + 512 + lane * 8);                                 \
        L0 = *(const bf16x8*)(pB_ + 1024 + lane * 8);                                \
        L1 = *(const bf16x8*)(pB_ + 1536 + lane * 8);                                \
    } while (0)

#define COMPUTE(BH0, BH1, BL0, BL1, JT)                                              \
    do {                                                                             \
        const int j0_ = jChunk0 + (JT) * 16;                                         \
        _Pragma("unroll")                                                            \
        for (int s = 0; s < 4; s++) {                                                \
            f32x4 p_, q_;                                                            \
            p_ = __builtin_amdgcn_mfma_f32_16x16x32_bf16(aHi[s][0], BH0, zq, 0, 0, 0);  \
            q_ = __builtin_amdgcn_mfma_f32_16x16x32_bf16(aLo[s][1], BH1, zq, 0, 0, 0);  \
            p_ = __builtin_amdgcn_mfma_f32_16x16x32_bf16(aHi[s][1], BH1, p_, 0, 0, 0);  \
            q_ = __builtin_amdgcn_mfma_f32_16x16x32_bf16(aHi[s][0], BL0, q_, 0, 0, 0);  \
            p_ = __builtin_amdgcn_mfma_f32_16x16x32_bf16(aLo[s][0], BH0, p_, 0, 0, 0);  \
            q_ = __builtin_amdgcn_mfma_f32_16x16x32_bf16(aHi[s][1], BL1, q_, 0, 0, 0);  \
            f32x4 acc = p_ + q_;                                                     \
            if (sUni[s] && j0_ >= sLo[s] && j0_ + 16 <= sHi[s]) {                    \
                _Pragma("unroll")                                                    \
                for (int r = 0; r < 4; r++) mn[s][r] = fminf(mn[s][r], acc[r]);      \
            } else if (sUni[s] && (j0_ >= sHi[s] || j0_ + 16 <= sLo[s])) {           \
                _Pragma("unroll")                                                    \
                for (int r = 0; r < 4; r++) mx[s][r] = fmaxf(mx[s][r], acc[r]);      \
            } else {                                                                 \
                int fj_ = famSorted[j0_ + c];                                        \
                unsigned fi4_ = *(const unsigned*)(famSorted + rowBase + s * 16 + g * 4); \
                _Pragma("unroll")                                                    \
                for (int r = 0; r < 4; r++) {                                        \
                    int fir_ = (int)((fi4_ >> (8 * r)) & 255u);                      \
                    bool same_ = (fir_ == fj_);                                      \
                    float d_ = acc[r];                                               \
                    mn[s][r] = fminf(mn[s][r], same_ ? d_ : 1e30f);                  \
                    mx[s][r] = fmaxf(mx[s][r], same_ ? -1e30f : d_);                 \
                }                                                                    \
            }                                                                        \
        }                                                                            \
    } while (0)

#define FENCE() __builtin_amdgcn_sched_barrier(0)

__global__ __launch_bounds__(256) void gemm_minmax_kernel(
    const short* __restrict__ pack,
    const unsigned char* __restrict__ famSorted, const int* __restrict__ famLoHi,
    float* __restrict__ pMin, float* __restrict__ pMax, int B) {
    const int lane = threadIdx.x & 63;
    const int wid  = threadIdx.x >> 6;
    const int g = lane >> 4;
    const int c = lane & 15;
    const int rowBase = blockIdx.x * 256 + wid * 64;
    const int aStrip0 = rowBase >> 4;

    // A fragments: 4 strips x {h0,h1,l0,l1}. 64 VGPRs, resident all sweep.
    bf16x8 aHi[4][2], aLo[4][2];
#pragma unroll
    for (int s = 0; s < 4; s++) {
        const short* pA = pack + (size_t)(aStrip0 + s) * 2048;
        aHi[s][0] = *(const bf16x8*)(pA + lane * 8);
        aHi[s][1] = *(const bf16x8*)(pA + 512 + lane * 8);
        aLo[s][0] = *(const bf16x8*)(pA + 1024 + lane * 8);
        aLo[s][1] = *(const bf16x8*)(pA + 1536 + lane * 8);
    }

    // Per-strip family classification (rows sorted -> piecewise constant).
    int sLo[4], sHi[4], sUni[4];
#pragma unroll
    for (int s = 0; s < 4; s++) {
        int f0  = famSorted[rowBase + s * 16];
        int f15 = famSorted[rowBase + s * 16 + 15];
        sUni[s] = __builtin_amdgcn_readfirstlane((f0 == f15) ? 1 : 0);
        sLo[s]  = __builtin_amdgcn_readfirstlane(famLoHi[f0]);
        sHi[s]  = __builtin_amdgcn_readfirstlane(famLoHi[4 + f0]);
    }

    const f32x4 zq = {0.f, 0.f, 0.f, 0.f};
    f32x4 mn[4], mx[4];
#pragma unroll
    for (int s = 0; s < 4; s++)
#pragma unroll
        for (int r = 0; r < 4; r++) { mn[s][r] = 1e30f; mx[s][r] = -1e30f; }

    const int jChunk0 = blockIdx.y * (B / NJ);
    const int jStrip0 = jChunk0 >> 4;
    const int NJT = (B / NJ) >> 4;  // 16, divisible by 4

    // Pinned software pipeline, prefetch distance 2, 4 rotating named buffers.
    bf16x8 b0h0, b0h1, b0l0, b0l1, b1h0, b1h1, b1l0, b1l1;
    bf16x8 b2h0, b2h1, b2l0, b2l1, b3h0, b3h1, b3l0, b3l1;
    LOADB(b0h0, b0h1, b0l0, b0l1, 0);
    LOADB(b1h0, b1h1, b1l0, b1l1, 1);
    FENCE();
    for (int jt = 0; jt < NJT; jt += 4) {
        if (jt + 2 < NJT) LOADB(b2h0, b2h1, b2l0, b2l1, jt + 2);
        FENCE();
        COMPUTE(b0h0, b0h1, b0l0, b0l1, jt);
        FENCE();
        if (jt + 3 < NJT) LOADB(b3h0, b3h1, b3l0, b3l1, jt + 3);
        FENCE();
        COMPUTE(b1h0, b1h1, b1l0, b1l1, jt + 1);
        FENCE();
        if (jt + 4 < NJT) LOADB(b0h0, b0h1, b0l0, b0l1, jt + 4);
        FENCE();
        COMPUTE(b2h0, b2h1, b2l0, b2l1, jt + 2);
        FENCE();
        if (jt + 5 < NJT) LOADB(b1h0, b1h1, b1l0, b1l1, jt + 5);
        FENCE();
        COMPUTE(b3h0, b3h1, b3l0, b3l1, jt + 3);
        FENCE();
    }

    // Reduce across the 16 column-lanes (same g), then write per-row partials.
#pragma unroll
    for (int s = 0; s < 4; s++)
#pragma unroll
        for (int r = 0; r < 4; r++) {
            float mnv = mn[s][r], mxv = mx[s][r];
#pragma unroll
            for (int o = 8; o > 0; o >>= 1) {
                mnv = fminf(mnv, __shfl_xor(mnv, o, 64));
                mxv = fmaxf(mxv, __shfl_xor(mxv, o, 64));
            }
            if (c == 0) {
                int row = rowBase + s * 16 + g * 4 + r;  // sorted-row index
                pMin[(size_t)blockIdx.y * B + row] = mnv;
                pMax[(size_t)blockIdx.y * B + row] = mxv;
            }
        }
}

// ---------------- K4: per-row chunk combine + block partial sums ----------------
__global__ __launch_bounds__(256) void rowloss_kernel(const float* __restrict__ pMin,
                                                      const float* __restrict__ pMax,
                                                      float* __restrict__ partial, int B) {
    const int row = blockIdx.x * 256 + threadIdx.x;
    float mn = 1e30f, mx = -1e30f;
#pragma unroll 4
    for (int cn = 0; cn < NJ; cn++) {
        mn = fminf(mn, pMin[(size_t)cn * B + row]);
        mx = fmaxf(mx, pMax[(size_t)cn * B + row]);
    }
    float sum = 0.f, cnt = 0.f;
    if (mn < 1e29f && mx > -1e29f) {
        sum = fmaxf(mx - mn + MARGIN, 0.f);
        cnt = 1.f;
    }
#pragma unroll
    for (int o = 32; o > 0; o >>= 1) {
        sum += __shfl_xor(sum, o, 64);
        cnt += __shfl_xor(cnt, o, 64);
    }
    __shared__ float sS[4], sC[4];
    const int lane = threadIdx.x & 63, w = threadIdx.x >> 6;
    if (lane == 0) { sS[w] = sum; sC[w] = cnt; }
    __syncthreads();
    if (threadIdx.x == 0) {
        partial[blockIdx.x]      = sS[0] + sS[1] + sS[2] + sS[3];
        partial[64 + blockIdx.x] = sC[0] + sC[1] + sC[2] + sC[3];
    }
}

// ---------------- K5: deterministic final reduce ----------------
__global__ void final_kernel(const float* __restrict__ partial, float* __restrict__ out, int nb) {
    if (threadIdx.x == 0) {
        float S = 0.f, C = 0.f;
        for (int i = 0; i < nb; i++) { S += partial[i]; C += partial[64 + i]; }
        out[0] = S / fmaxf(C, 1.f);
    }
}

extern "C" void kernel_launch(void* const* d_in, const int* in_sizes, int n_in,
                              void* d_out, int out_size, void* d_ws, size_t ws_size,
                              hipStream_t stream) {
    const float* emb    = (const float*)d_in[0];
    const int*   labels = (const int*)d_in[1];
    const int B = in_sizes[1];  // 8192, D == 64

    char* base = (char*)d_ws;
    size_t off = 0;
    auto alloc = [&](size_t bytes) -> char* {
        char* p = base + off;
        off = (off + bytes + 255) & ~(size_t)255;
        return p;
    };
    int*           posOf     = (int*)alloc((size_t)B * 4);
    unsigned char* famSorted = (unsigned char*)alloc((size_t)B);
    int*           famLoHi   = (int*)alloc(32);
    short*         pack      = (short*)alloc((size_t)B * 128 * 2);  // merged hi/lo
    float*         pMin      = (float*)alloc((size_t)NJ * B * 4);
    float*         pMax      = (float*)alloc((size_t)NJ * B * 4);
    float*         partial   = (float*)alloc(128 * 4);

    sort_kernel<<<1, 1024, 0, stream>>>(labels, posOf, famSorted, famLoHi, B);
    normpack_kernel<<<B / 4, 256, 0, stream>>>(emb, posOf, pack, B);
    dim3 g3(B / 256, NJ);
    gemm_minmax_kernel<<<g3, 256, 0, stream>>>(pack, famSorted, famLoHi, pMin, pMax, B);
    rowloss_kernel<<<B / 256, 256, 0, stream>>>(pMin, pMax, partial, B);
    final_kernel<<<1, 64, 0, stream>>>(partial, (float*)d_out, B / 256);
}